// Round 16
// baseline (95.785 us; speedup 1.0000x reference)
//
#include <hip/hip_runtime.h>
#include <hip/hip_fp16.h>
#include <math.h>

typedef unsigned long long u64;

constexpr int B = 512, T = 512, C = 128, L = 64;
constexpr int BLANK = C - 1;      // 127
constexpr float INV_LN2 = 1.44269504088896f;
constexpr float LN2 = 0.69314718055995f;
constexpr int PITCH = 66;         // halves per LDS row in rowstats transpose

// ---------------------------------------------------------------------------
// async global->LDS (Myers staging only)
// ---------------------------------------------------------------------------
typedef const __attribute__((address_space(1))) void* gas_p;
typedef __attribute__((address_space(3))) void* las_p;
__device__ __forceinline__ void gload_lds16(const void* g, void* l) {
  __builtin_amdgcn_global_load_lds((gas_p)g, (las_p)l, 16, 0, 0);
}
#define WAIT_VM0() do { \
  asm volatile("s_waitcnt vmcnt(0)" ::: "memory"); \
  __builtin_amdgcn_sched_barrier(0); } while (0)

// ---------------------------------------------------------------------------
// DPP / lane helpers
// ---------------------------------------------------------------------------
__device__ __forceinline__ float dpp_shr1_f(float x, float old) {
  int r = __builtin_amdgcn_update_dpp(__float_as_int(old), __float_as_int(x),
                                      0x138, 0xf, 0xf, false);  // lane i <- i-1
  return __int_as_float(r);
}
__device__ __forceinline__ int dpp_shr1_i(int x, int old) {
  return __builtin_amdgcn_update_dpp(old, x, 0x138, 0xf, 0xf, false);
}
__device__ __forceinline__ float scan_max64(float x) {
  const int NI = (int)0xff800000;  // -inf
  int t;
  t = __builtin_amdgcn_update_dpp(NI, __float_as_int(x), 0x111, 0xf, 0xf, false);
  x = fmaxf(x, __int_as_float(t));
  t = __builtin_amdgcn_update_dpp(NI, __float_as_int(x), 0x112, 0xf, 0xf, false);
  x = fmaxf(x, __int_as_float(t));
  t = __builtin_amdgcn_update_dpp(NI, __float_as_int(x), 0x114, 0xf, 0xf, false);
  x = fmaxf(x, __int_as_float(t));
  t = __builtin_amdgcn_update_dpp(NI, __float_as_int(x), 0x118, 0xf, 0xf, false);
  x = fmaxf(x, __int_as_float(t));
  t = __builtin_amdgcn_update_dpp(NI, __float_as_int(x), 0x142, 0xa, 0xf, false);
  x = fmaxf(x, __int_as_float(t));
  t = __builtin_amdgcn_update_dpp(NI, __float_as_int(x), 0x143, 0xc, 0xf, false);
  x = fmaxf(x, __int_as_float(t));
  return x;  // lane63 = wave max
}
__device__ __forceinline__ float scan_add64(float x) {
  int t;
  t = __builtin_amdgcn_update_dpp(0, __float_as_int(x), 0x111, 0xf, 0xf, false);
  x += __int_as_float(t);
  t = __builtin_amdgcn_update_dpp(0, __float_as_int(x), 0x112, 0xf, 0xf, false);
  x += __int_as_float(t);
  t = __builtin_amdgcn_update_dpp(0, __float_as_int(x), 0x114, 0xf, 0xf, false);
  x += __int_as_float(t);
  t = __builtin_amdgcn_update_dpp(0, __float_as_int(x), 0x118, 0xf, 0xf, false);
  x += __int_as_float(t);
  t = __builtin_amdgcn_update_dpp(0, __float_as_int(x), 0x142, 0xa, 0xf, false);
  x += __int_as_float(t);
  t = __builtin_amdgcn_update_dpp(0, __float_as_int(x), 0x143, 0xc, 0xf, false);
  x += __int_as_float(t);
  return x;  // lane63 = wave sum
}
__device__ __forceinline__ float readlane63(float x) {
  return __int_as_float(__builtin_amdgcn_readlane(__float_as_int(x), 63));
}

// ---------------------------------------------------------------------------
// K1: per-(b,t) row stats. Writes:
//   rtab[b][j][t] f16 = p_label/p_blank (transposed, 512 halves/row)
//   p_blh[b][t] f16 (fallback), predc u8, eqm u64 ballot (Myers Peq),
//   pbsum_part[b*8+chunk] f32 = sum of log2(p_blank) over the chunk.
// ---------------------------------------------------------------------------
__global__ __launch_bounds__(256) void rowstats_kernel(
    const float* __restrict__ logits, const int* __restrict__ labels,
    __half* __restrict__ rtab, __half* __restrict__ p_blh,
    unsigned char* __restrict__ predc, u64* __restrict__ eqm,
    float* __restrict__ pbsum_part) {
  __shared__ __half slp[64 * PITCH];
  __shared__ float sp[4];
  int b = blockIdx.x & 511;
  int chunk = blockIdx.x >> 9;
  int t0 = chunk << 6;
  int w = threadIdx.x >> 6;
  int lane = threadIdx.x & 63;
  int lab = labels[((size_t)b << 6) + lane];
  float acc = 0.0f;
  for (int i = 0; i < 16; ++i) {
    int t = t0 + w * 16 + i;
    const float* rp = logits + (size_t)(b * T + t) * C;
    float v1 = rp[lane];
    float v2 = rp[lane + 64];
    float m = readlane63(scan_max64(fmaxf(v1, v2)));
    unsigned long long b1 = __ballot(v1 == m);
    unsigned long long b2 = __ballot(v2 == m);
    int idx = b1 ? (__ffsll(b1) - 1) : (64 + __ffsll(b2) - 1);
    u64 eqmask = __ballot(lab == idx);
    float e1 = __builtin_amdgcn_exp2f((v1 - m) * INV_LN2);
    float e2 = __builtin_amdgcn_exp2f((v2 - m) * INV_LN2);
    float rs = __builtin_amdgcn_rcpf(readlane63(scan_add64(e1 + e2)));
    float p1 = e1 * rs;
    float p2 = e2 * rs;        // lane63: blank prob
    acc += __builtin_amdgcn_logf(p2);   // log2; only lane63's acc used
    float pbv = readlane63(p2);
    float g1 = __shfl(p1, lab & 63);
    float g2 = __shfl(p2, lab & 63);
    float gp = (lab < 64) ? g1 : g2;
    float ratio = gp * __builtin_amdgcn_rcpf(pbv);
    slp[lane * PITCH + (t - t0)] = __float2half(ratio);
    if (lane == 63) p_blh[b * T + t] = __float2half(p2);
    if (lane == 0) { predc[b * T + t] = (unsigned char)idx; eqm[b * T + t] = eqmask; }
  }
  if (lane == 63) sp[w] = acc;
  __syncthreads();
  if (threadIdx.x == 0)
    pbsum_part[(b << 3) + chunk] = sp[0] + sp[1] + sp[2] + sp[3];
  int j = threadIdx.x >> 2, q = threadIdx.x & 3;
  unsigned wbuf[8];
#pragma unroll
  for (int wd = 0; wd < 8; ++wd)
    wbuf[wd] = ((const unsigned*)slp)[j * (PITCH / 2) + q * 8 + wd];
  uint4 o0 = make_uint4(wbuf[0], wbuf[1], wbuf[2], wbuf[3]);
  uint4 o1 = make_uint4(wbuf[4], wbuf[5], wbuf[6], wbuf[7]);
  uint4* dst = (uint4*)(rtab + ((size_t)((b << 6) + j)) * 512 + t0 + q * 16);
  dst[0] = o0;
  dst[1] = o1;
}

// extract half #k (0..15) from 2 uint4 regs (k compile-time)
__device__ __forceinline__ float geth16(const uint4& v0, const uint4& v1, int k) {
  const uint4& v = (k < 8) ? v0 : v1;
  int c2 = (k >> 1) & 3;
  unsigned comp = (c2 == 0) ? v.x : (c2 == 1) ? v.y : (c2 == 2) ? v.z : v.w;
  unsigned hs = (k & 1) ? (comp >> 16) : (comp & 0xffffu);
  unsigned short us = (unsigned short)hs;
  __half h;
  __builtin_memcpy(&h, &us, 2);
  return __half2float(h);
}

// ---------------------------------------------------------------------------
// beta-normalized forward step (state0 == 1 identically).
// Lane j: qO = beta-alpha[2j+1], qE = beta-alpha[2j+2], scale 2^m.
// ---------------------------------------------------------------------------
__device__ __forceinline__ void fstep(float rv, bool skip_ok,
                                      float& qE, float& qO, int& m) {
  float pE = dpp_shr1_f(qE, 1.0f);    // alpha[2j] (lane0 <- state0 == 1)
  float pO = dpp_shr1_f(qO, 0.0f);    // alpha[2j-1]
  int mN = dpp_shr1_i(m, 0);
  int dm = mN - m;
  float pEs = ldexpf(pE, dm);
  float a3 = skip_ok ? ldexpf(pO, dm) : 0.0f;
  float nO = (qO + pEs + a3) * rv;
  float nE = qE + qO;
  qO = nO; qE = nE;
}
__device__ __forceinline__ void frenorm(float& qE, float& qO, int& m) {
  float mx = fmaxf(qE, qO);
  int mprev = dpp_shr1_i(m, 0);
  int e = (__float_as_int(mx) >> 23) & 0xff;
  int sh = e - 127;
  qE = ldexpf(qE, -sh);
  qO = ldexpf(qO, -sh);
  m = (mx == 0.0f) ? mprev : (m + sh);
}

// beta (backward) step, t descending. bO = beta[2j+1], bE = beta[2j+2].
__device__ __forceinline__ void gstep(float rv, bool skipG, int lane,
                                      float& bE, float& bO, int& m,
                                      float& b0, int& mb0) {
  float bOu_raw = __shfl_down(bO, 1);
  int mu = __shfl_down(m, 1);
  int dm = mu - m;
  float bOu = (lane < 63) ? ldexpf(bOu_raw, dm) : 0.0f;
  // state-0 chain (meaningful on lane 0): b0 += bO * 2^(m-mb0), init-aware
  bool fresh = (b0 == 0.0f);
  float add = ldexpf(bO, fresh ? 0 : (m - mb0));
  b0 = fresh ? bO : (b0 + add);
  mb0 = fresh ? m : mb0;
  float nO = (bO + bE + (skipG ? bOu : 0.0f)) * rv;
  float nE = bE + bOu;
  bO = nO; bE = nE;
}
__device__ __forceinline__ void grenorm(float& bE, float& bO, int& m,
                                        float& b0, int& mb0) {
  int mu2 = __shfl_down(m, 1);
  float mx = fmaxf(bO, bE);
  int e = (__float_as_int(mx) >> 23) & 0xff;
  int sh = e - 127;
  bO = ldexpf(bO, -sh);
  bE = ldexpf(bE, -sh);
  m = (mx == 0.0f) ? mu2 : (m + sh);
  int eb = (b0 == 0.0f) ? 0 : (((__float_as_int(b0) >> 23) & 0xff) - 127);
  b0 = ldexpf(b0, -eb);
  mb0 += eb;
}

// Myers/Hyyrö bit-parallel Levenshtein step (lane = one sample; select-only).
__device__ __forceinline__ void ed_step(u64 eq, int cc, int shift, bool tok,
                                        u64& Pv, u64& Mv, int& score, int& prevc) {
  bool keep = (cc != BLANK) && (cc != prevc) && tok;
  u64 Xv = eq | Mv;
  u64 Xh = (((eq & Pv) + Pv) ^ Pv) | eq;
  u64 Ph = Mv | ~(Xh | Pv);
  u64 Mh = Pv & Xh;
  int d = (int)((Ph >> shift) & 1ULL) - (int)((Mh >> shift) & 1ULL);
  score += keep ? d : 0;
  Ph = (Ph << 1) | 1ULL;
  Mh <<= 1;
  u64 nPv = Mh | ~(Xv | Ph);
  u64 nMv = Ph & Xv;
  Pv = keep ? nPv : Pv;
  Mv = keep ? nMv : Mv;
  prevc = cc;
}

// ---------------------------------------------------------------------------
// K2: blocks [0,8) Myers; [8,520) forward half (alpha, t<256, then propagate);
// [520,1032) backward half (beta, t>=256). F and G run CONCURRENTLY -> the
// sequential depth per wave is halved (256 steps).
// ---------------------------------------------------------------------------
__global__ __launch_bounds__(64, 1) void dp_kernel(
    const __half* __restrict__ rtab, const __half* __restrict__ p_blh,
    const unsigned char* __restrict__ predc, const u64* __restrict__ eqm,
    const int* __restrict__ labels, const int* __restrict__ label_len,
    const int* __restrict__ logit_len, const float* __restrict__ pbsum_part,
    float* __restrict__ fAE, float* __restrict__ fAO, int* __restrict__ fM,
    float* __restrict__ gBE, float* __restrict__ gBO, int* __restrict__ gM,
    float* __restrict__ gB0, int* __restrict__ gMB0,
    float* __restrict__ loss_b, float* __restrict__ ler_b) {
  __shared__ char smem[18432];
  int lane = threadIdx.x;

  if (blockIdx.x >= 8 && blockIdx.x < 8 + (unsigned)B) {
    // ---------------- F: forward alpha over t in [0,256) ----------------
    int b = blockIdx.x - 8;
    int tl = logit_len[b];
    int ll = label_len[b];
    int lab = labels[((size_t)b << 6) + lane];
    int labp = __shfl_up(lab, 1);
    bool skip_ok = (lane > 0) && (lab != labp);
    const uint4* pl4 = (const uint4*)(rtab + ((size_t)((b << 6) + lane)) * 512);
    float qE = 0.0f, qO;
    int m = 0;

    if (tl == T) {
      uint4 A0 = pl4[0], A1 = pl4[1];
      uint4 B0 = pl4[2], B1 = pl4[3];
      // group 0 (peeled t=0 init)
      qO = (lane == 0) ? geth16(A0, A1, 0) : 0.0f;
#pragma unroll
      for (int k = 1; k < 16; ++k) {
        fstep(geth16(A0, A1, k), skip_ok, qE, qO, m);
        if ((k & 3) == 3) frenorm(qE, qO, m);
      }
      A0 = pl4[4]; A1 = pl4[5];
#pragma unroll 1
      for (int g = 1; g < 15; g += 2) {
#pragma unroll
        for (int k = 0; k < 16; ++k) {
          fstep(geth16(B0, B1, k), skip_ok, qE, qO, m);
          if ((k & 3) == 3) frenorm(qE, qO, m);
        }
        B0 = pl4[(g + 2) * 2]; B1 = pl4[(g + 2) * 2 + 1];
#pragma unroll
        for (int k = 0; k < 16; ++k) {
          fstep(geth16(A0, A1, k), skip_ok, qE, qO, m);
          if ((k & 3) == 3) frenorm(qE, qO, m);
        }
        A0 = pl4[(g + 3) * 2]; A1 = pl4[(g + 3) * 2 + 1];
      }
#pragma unroll
      for (int k = 0; k < 16; ++k) {   // group 15
        fstep(geth16(B0, B1, k), skip_ok, qE, qO, m);
        if ((k & 3) == 3) frenorm(qE, qO, m);
      }
      // junction propagate (transition 255 -> 256, no emission)
      float pE = dpp_shr1_f(qE, 1.0f);
      float pO = dpp_shr1_f(qO, 0.0f);
      int mN = dpp_shr1_i(m, 0);
      int dm = mN - m;
      float aOp = qO + ldexpf(pE, dm) + (skip_ok ? ldexpf(pO, dm) : 0.0f);
      float aEp = qE + qO;
      fAE[(b << 6) + lane] = aEp;
      fAO[(b << 6) + lane] = aOp;
      fM[(b << 6) + lane] = m;
    } else {
      // serial fallback: full recursion in this wave, writes loss directly
      const __half* rr = (const __half*)pl4;
      qO = (lane == 0) ? __half2float(rr[0]) : 0.0f;
      for (int t = 1; t < tl; ++t) {
        fstep(__half2float(rr[t]), skip_ok, qE, qO, m);
        if ((t & 3) == 3) frenorm(qE, qO, m);
      }
      float e1 = __shfl(qE, ll - 1);
      float e2 = __shfl(qO, ll - 1);
      int msel = __shfl(m, ll - 1);
      if (lane == 0) {
        float spb = 0.0f;
        for (int t = 0; t < tl; ++t)
          spb += __builtin_amdgcn_logf(__half2float(p_blh[b * T + t]));
        loss_b[b] = -((float)msel + __builtin_amdgcn_logf(e1 + e2) + spb) * LN2;
      }
    }
  } else if (blockIdx.x >= 8 + (unsigned)B) {
    // ---------------- G: backward beta over t in [256,512) ----------------
    int b = blockIdx.x - 8 - B;
    int tl = logit_len[b];
    if (tl != T) return;   // fallback handled entirely by F wave
    int ll = label_len[b];
    int lab = labels[((size_t)b << 6) + lane];
    int labn = __shfl_down(lab, 1);
    bool skipG = (lane < 63) && (labn != lab);
    const uint4* pl4 = (const uint4*)(rtab + ((size_t)((b << 6) + lane)) * 512);
    float bE, bO, b0 = 0.0f;
    int m = 0, mb0 = 0;

    // group 0: t in [496,511]; init at t=511 (k=15), steps k=14..0
    uint4 A0 = pl4[62], A1 = pl4[63];
    uint4 B0 = pl4[60], B1 = pl4[61];
    bO = (lane == ll - 1) ? geth16(A0, A1, 15) : 0.0f;
    bE = (lane == ll - 1) ? 1.0f : 0.0f;
#pragma unroll
    for (int kk = 1; kk < 16; ++kk) {
      int k = 15 - kk;
      gstep(geth16(A0, A1, k), skipG, lane, bE, bO, m, b0, mb0);
      if ((k & 3) == 0) grenorm(bE, bO, m, b0, mb0);
    }
    A0 = pl4[58]; A1 = pl4[59];        // group 2 (base uint4 = 62-2g)
#pragma unroll 1
    for (int g = 1; g < 15; g += 2) {
#pragma unroll
      for (int kk = 0; kk < 16; ++kk) {
        int k = 15 - kk;
        gstep(geth16(B0, B1, k), skipG, lane, bE, bO, m, b0, mb0);
        if ((k & 3) == 0) grenorm(bE, bO, m, b0, mb0);
      }
      B0 = pl4[62 - 2 * (g + 2)]; B1 = pl4[63 - 2 * (g + 2)];
#pragma unroll
      for (int kk = 0; kk < 16; ++kk) {
        int k = 15 - kk;
        gstep(geth16(A0, A1, k), skipG, lane, bE, bO, m, b0, mb0);
        if ((k & 3) == 0) grenorm(bE, bO, m, b0, mb0);
      }
      A0 = pl4[62 - 2 * (g + 3)]; A1 = pl4[63 - 2 * (g + 3)];
    }
#pragma unroll
    for (int kk = 0; kk < 16; ++kk) {  // group 15: t in [256,271]
      int k = 15 - kk;
      gstep(geth16(B0, B1, k), skipG, lane, bE, bO, m, b0, mb0);
      if ((k & 3) == 0) grenorm(bE, bO, m, b0, mb0);
    }
    gBE[(b << 6) + lane] = bE;
    gBO[(b << 6) + lane] = bO;
    gM[(b << 6) + lane] = m;
    if (lane == 0) { gB0[b] = b0; gMB0[b] = mb0; }
  } else {
    // ---------------- Myers edit distance (lane = sample) ----------------
    int bb = (blockIdx.x << 6) + lane;
    int tl = logit_len[bb];
    int ll = label_len[bb];
    int shift = ll - 1;
    u64 Pv = ~0ULL, Mv = 0ULL;
    int score = ll;
    int prevc = 255;
    const char* eqB = (const char*)(eqm + (size_t)bb * T);
    const char* pqB = (const char*)(predc + (size_t)bb * T);
    auto stage = [&](int c, int s) {
      char* Eb = smem + s * 9216;
#pragma unroll
      for (int k = 0; k < 8; ++k)
        gload_lds16(eqB + (size_t)c * 128 + k * 16, Eb + k * 1024);
      gload_lds16(pqB + (size_t)c * 16, Eb + 8192);
    };
    stage(0, 0);
    WAIT_VM0();
    stage(1, 1);
#pragma unroll 1
    for (int c = 0; c < 32; ++c) {
      int s = c & 1;
      if (c) {
        WAIT_VM0();
        if (c < 31) stage(c + 1, s ^ 1);
      }
      const char* base = smem + s * 9216;
#pragma unroll
      for (int k = 0; k < 16; ++k) {
        u64 eq = *(const u64*)(base + (k >> 1) * 1024 + lane * 16 + (k & 1) * 8);
        int cc = *(const unsigned char*)(base + 8192 + lane * 16 + k);
        ed_step(eq, cc, shift, c * 16 + k < tl, Pv, Mv, score, prevc);
      }
    }
    ler_b[bb] = (float)score / (float)ll;
  }
}

// ---------------------------------------------------------------------------
// K3: combine F and G halves: L = sum_s propagate(alpha_255)[s]*beta_256[s].
// One wave per sample; per-lane scaled terms, max-scale wave reduction.
// ---------------------------------------------------------------------------
__global__ __launch_bounds__(64) void combine_kernel(
    const float* __restrict__ fAE, const float* __restrict__ fAO,
    const int* __restrict__ fM, const float* __restrict__ gBE,
    const float* __restrict__ gBO, const int* __restrict__ gM,
    const float* __restrict__ gB0, const int* __restrict__ gMB0,
    const float* __restrict__ pbsum_part, const int* __restrict__ logit_len,
    float* __restrict__ loss_b) {
  int b = blockIdx.x;
  if (logit_len[b] != T) return;   // loss already written by F fallback
  int lane = threadIdx.x;
  float aE = fAE[(b << 6) + lane];
  float aO = fAO[(b << 6) + lane];
  float bE = gBE[(b << 6) + lane];
  float bO = gBO[(b << 6) + lane];
  int ms = fM[(b << 6) + lane] + gM[(b << 6) + lane];
  float b0 = gB0[b];
  int mb0 = gMB0[b];
  float term = aO * bO + aE * bE;
  float msf = (term > 0.0f) ? (float)ms : -3e38f;
  float M = readlane63(scan_max64(msf));
  M = fmaxf(M, (b0 > 0.0f) ? (float)mb0 : -3e38f);  // state-0 term (a'[0]=1)
  int Mi = (int)M;
  float s = ldexpf(term, ms - Mi);
  float S = readlane63(scan_add64(s));
  S += ldexpf(b0, mb0 - Mi);
  if (lane == 0) {
    float spb = 0.0f;
#pragma unroll
    for (int c = 0; c < 8; ++c) spb += pbsum_part[(b << 3) + c];
    loss_b[b] = -(M + __builtin_amdgcn_logf(S) + spb) * LN2;
  }
}

// ---------------------------------------------------------------------------
// K4: deterministic final mean over B for loss and ler.
// ---------------------------------------------------------------------------
__global__ __launch_bounds__(512) void reduce_kernel(
    const float* __restrict__ loss_b, const float* __restrict__ ler_b,
    float* __restrict__ out) {
  __shared__ float sl[512];
  __shared__ float sr[512];
  int tid = threadIdx.x;
  sl[tid] = loss_b[tid];
  sr[tid] = ler_b[tid];
  __syncthreads();
  for (int off = 256; off; off >>= 1) {
    if (tid < off) { sl[tid] += sl[tid + off]; sr[tid] += sr[tid + off]; }
    __syncthreads();
  }
  if (tid == 0) {
    out[0] = sl[0] / (float)B;
    out[1] = sr[0] / (float)B;
  }
}

extern "C" void kernel_launch(void* const* d_in, const int* in_sizes, int n_in,
                              void* d_out, int out_size, void* d_ws, size_t ws_size,
                              hipStream_t stream) {
  const int*   labels    = (const int*)d_in[0];
  const float* logits    = (const float*)d_in[1];
  const int*   label_len = (const int*)d_in[2];
  const int*   logit_len = (const int*)d_in[3];
  float* out = (float*)d_out;

  char* ws = (char*)d_ws;
  size_t off = 0;
  __half* rtab  = (__half*)(ws + off); off += (size_t)B * 64 * 512 * 2;  // 32MB
  __half* p_blh = (__half*)(ws + off); off += (size_t)B * T * 2;
  u64*    eqm   = (u64*)(ws + off);    off += (size_t)B * T * 8;
  unsigned char* predc = (unsigned char*)(ws + off); off += (size_t)B * T;
  float* pbsum_part = (float*)(ws + off); off += (size_t)B * 8 * 4;
  float* fAE = (float*)(ws + off); off += (size_t)B * 64 * 4;
  float* fAO = (float*)(ws + off); off += (size_t)B * 64 * 4;
  int*   fM  = (int*)(ws + off);   off += (size_t)B * 64 * 4;
  float* gBE = (float*)(ws + off); off += (size_t)B * 64 * 4;
  float* gBO = (float*)(ws + off); off += (size_t)B * 64 * 4;
  int*   gM  = (int*)(ws + off);   off += (size_t)B * 64 * 4;
  float* gB0 = (float*)(ws + off); off += (size_t)B * 4;
  int*   gMB0 = (int*)(ws + off);  off += (size_t)B * 4;
  float* loss_b = (float*)(ws + off); off += (size_t)B * 4;
  float* ler_b  = (float*)(ws + off);

  rowstats_kernel<<<B * (T / 64), 256, 0, stream>>>(logits, labels, rtab,
                                                    p_blh, predc, eqm,
                                                    pbsum_part);
  dp_kernel<<<8 + 2 * B, 64, 0, stream>>>(rtab, p_blh, predc, eqm, labels,
                                          label_len, logit_len, pbsum_part,
                                          fAE, fAO, fM, gBE, gBO, gM, gB0,
                                          gMB0, loss_b, ler_b);
  combine_kernel<<<B, 64, 0, stream>>>(fAE, fAO, fM, gBE, gBO, gM, gB0, gMB0,
                                       pbsum_part, logit_len, loss_b);
  reduce_kernel<<<1, 512, 0, stream>>>(loss_b, ler_b, out);
}